// Round 10
// baseline (111.617 us; speedup 1.0000x reference)
//
#include <hip/hip_runtime.h>
#include <hip/hip_bf16.h>

using bf16x8 = __attribute__((ext_vector_type(8))) short;
using f32x4  = __attribute__((ext_vector_type(4))) float;

static __device__ __forceinline__ short f2bf(float f) {
  union { float f; unsigned u; } x; x.f = f;
  unsigned r = x.u + 0x7fffu + ((x.u >> 16) & 1u);
  return (short)(r >> 16);
}
static __device__ __forceinline__ float bf2f(short b) {
  union { unsigned u; float f; } x; x.u = ((unsigned)(unsigned short)b) << 16;
  return x.f;
}
static __device__ __forceinline__ unsigned pack_bf2(float lo, float hi) {
  __hip_bfloat162 h = __float22bfloat162_rn(float2{lo, hi});   // v_cvt_pk_bf16_f32
  unsigned u; __builtin_memcpy(&u, &h, 4); return u;
}
static __device__ __forceinline__ float exp2_raw(float x) {
  float r; asm("v_exp_f32 %0, %1" : "=v"(r) : "v"(x)); return r;  // 1 inst, no libm fixups
}
static __device__ __forceinline__ void gll16(const void* g, void* l) {
  __builtin_amdgcn_global_load_lds((__attribute__((address_space(1))) const void*)g,
                                   (__attribute__((address_space(3))) void*)l, 16, 0, 0);
}

// ---------------- fused prep: cvt q / cvt k / 3x W-transpose / mask-pack ----------------
// one launch, roles by blockIdx.x range:
//   [0,1024)      : query f32 -> bf16
//   [1024,2048)   : key   f32 -> bf16
//   [2048,5120)   : W{q,k,p} transpose+cvt (1024 blocks each)
//   [5120,7168)   : mask -> bit-packed u64 per (row, 64-key tile)
__global__ void k_prep(const float* __restrict__ query, const float* __restrict__ key_in,
                       const float* __restrict__ Wq, const float* __restrict__ Wk,
                       const float* __restrict__ Wp,
                       const unsigned* __restrict__ mask_u32,
                       short* __restrict__ Qbf, short* __restrict__ Kbf,
                       short* __restrict__ Wt3, unsigned long long* __restrict__ packb) {
  const int bid = blockIdx.x, tid = threadIdx.x;
  if (bid < 2048) {                       // f32 -> bf16, 4M elems each
    const float* in = bid < 1024 ? query : key_in;
    short* out = bid < 1024 ? Qbf : Kbf;
    const int r = bid & 1023;
    const int n4 = (4 * 1024 * 1024) / 4;
    for (int i = r * 256 + tid; i < n4; i += 1024 * 256) {
      float4 v = reinterpret_cast<const float4*>(in)[i];
      short4 o;
      o.x = f2bf(v.x); o.y = f2bf(v.y); o.z = f2bf(v.z); o.w = f2bf(v.w);
      reinterpret_cast<short4*>(out)[i] = o;
    }
  } else if (bid < 5120) {                // W[k][n] -> bf16 Wt[n][k]
    __shared__ float tile[32][33];
    const int sub = bid - 2048;
    const int w = sub >> 10, s2 = sub & 1023;
    const int bx = s2 & 31, by = s2 >> 5;
    const float* in = w == 0 ? Wq : (w == 1 ? Wk : Wp);
    short* out = Wt3 + (size_t)w * 1024 * 1024;
    const int tx = tid & 31, ty = tid >> 5;
    int x = bx * 32 + tx, y0 = by * 32;
    for (int j = 0; j < 32; j += 8)
      tile[ty + j][tx] = in[(size_t)(y0 + ty + j) * 1024 + x];
    __syncthreads();
    int xo = by * 32 + tx, yo = bx * 32;
    for (int j = 0; j < 32; j += 8)
      out[(size_t)(yo + ty + j) * 1024 + xo] = f2bf(tile[tx][ty + j]);
  } else {                                // mask pack (dtype auto-detect)
    const int r = bid - 5120;
    unsigned probe = mask_u32[tid & 63];
    const bool u8mode = (__ballot(probe > 1u) != 0ull);
    const unsigned char* s8 = (const unsigned char*)mask_u32;
    const int* s32 = (const int*)mask_u32;
    const int n = 4 * 1024 * 1024;
    for (int e = r * 256 + tid; e < n; e += 2048 * 256) {
      int v = u8mode ? (int)s8[e] : s32[e];
      unsigned long long b = __ballot(v != 0);
      if ((tid & 63) == 0) packb[e >> 6] = b;
    }
  }
}

// ---------------- bf16 MFMA GEMM body: C = A @ Bt^T + bias ----------------
// 128xBN tile, 4 waves (2x2), BK=64, 2-buffer, early-issue stage -> compute
// -> vmcnt(0)+barrier. Conflict-free chunk^row swizzle.
// VT_OUT: additionally emit the per-head-transposed tile to Vtg (Q-projection):
//   Vtg[(b*16+h)*64+d][s] — via 32KB LDS re-layout T[d_loc][s ^ ((d&7)<<4)].
template<int OUT_BF16, int BN, int M, int N, int K, int VT_OUT>
__device__ __forceinline__ void gemm_body(const short* __restrict__ A,
                                          const short* __restrict__ Bt,
                                          const float* __restrict__ bias,
                                          void* __restrict__ C,
                                          short* __restrict__ Vtg) {
  __shared__ short Al[2][128 * 64];
  __shared__ short Bl[2][BN * 64];
  constexpr int JF = BN / 32;        // N-frags per wave (wave covers BN/2 cols)
  const int tid  = threadIdx.x;
  const int lane = tid & 63, wid = tid >> 6;
  const int g = lane >> 4, lr = lane & 15;
  const int wm = wid >> 1, wn = wid & 1;
  constexpr int nbx = N / BN;
  constexpr int nwg = nbx * (M >> 7);
  const int lin = blockIdx.y * nbx + blockIdx.x;
  const int orig = (lin & 7) * (nwg >> 3) + (lin >> 3);   // XCD swizzle (nwg % 8 == 0)
  const int m0 = (orig / nbx) * 128, n0 = (orig % nbx) * BN;
  const int srow = lane >> 3;
  const int sch  = ((lane & 7) ^ srow) * 8;     // source chunk swizzle (row&7 == srow)

  f32x4 acc[4][JF];
#pragma unroll
  for (int i = 0; i < 4; ++i)
#pragma unroll
    for (int j = 0; j < JF; ++j) acc[i][j] = (f32x4){0.f, 0.f, 0.f, 0.f};

  constexpr int NT = K >> 6;
  auto stage = [&](int buf, int kt) {
#pragma unroll
    for (int s = 0; s < 4; ++s)
      gll16(&A[(size_t)(m0 + s * 32 + wid * 8 + srow) * K + kt + sch],
            &Al[buf][(s * 32 + wid * 8) * 64]);
#pragma unroll
    for (int s = 0; s < BN / 32; ++s)
      gll16(&Bt[(size_t)(n0 + s * 32 + wid * 8 + srow) * K + kt + sch],
            &Bl[buf][(s * 32 + wid * 8) * 64]);
  };

  stage(0, 0);
  asm volatile("s_waitcnt vmcnt(0)" ::: "memory");
  __builtin_amdgcn_s_barrier();
  asm volatile("" ::: "memory");

#pragma unroll 1
  for (int t = 0; t < NT; ++t) {
    const int cur = t & 1;
    if (t + 1 < NT) stage(cur ^ 1, (t + 1) * 64);   // readers of that buf done last iter
#pragma unroll
    for (int kb = 0; kb < 2; ++kb) {
      const int cs = ((kb * 4 + g) ^ (lr & 7)) * 8;      // swizzled read chunk
      bf16x8 af[4], bfr[JF];
#pragma unroll
      for (int i = 0; i < 4; ++i)
        af[i] = *reinterpret_cast<const bf16x8*>(&Al[cur][(wm * 64 + i * 16 + lr) * 64 + cs]);
#pragma unroll
      for (int j = 0; j < JF; ++j)
        bfr[j] = *reinterpret_cast<const bf16x8*>(
            &Bl[cur][(wn * (BN / 2) + j * 16 + lr) * 64 + cs]);
#pragma unroll
      for (int i = 0; i < 4; ++i)
#pragma unroll
        for (int j = 0; j < JF; ++j)
          acc[i][j] = __builtin_amdgcn_mfma_f32_16x16x32_bf16(af[i], bfr[j], acc[i][j], 0, 0, 0);
    }
    if (t + 1 < NT) {
      asm volatile("s_waitcnt vmcnt(0)" ::: "memory");  // stage(t+1) complete (had full flight)
      __builtin_amdgcn_s_barrier();                     // + everyone done reading cur
      asm volatile("" ::: "memory");
    }
  }

  // C store (+ optionally collect bf16 for the VT epilogue)
#pragma unroll
  for (int i = 0; i < 4; ++i) {
    int row = m0 + wm * 64 + i * 16 + g * 4;
#pragma unroll
    for (int j = 0; j < JF; ++j) {
      int col = n0 + wn * (BN / 2) + j * 16 + lr;
      float bv = bias[col];
#pragma unroll
      for (int r = 0; r < 4; ++r) {
        float v = acc[i][j][r] + bv;
        if (OUT_BF16) ((short*)C)[(size_t)(row + r) * N + col] = f2bf(v);
        else          ((float*)C)[(size_t)(row + r) * N + col] = v;
      }
    }
  }

  if (VT_OUT) {
    // Phase A: frags -> T LDS, layout T[d_loc][s_loc ^ ((d_loc&7)<<4)] over Al (32KB)
    short* T = (short*)Al;
    __builtin_amdgcn_s_barrier();   // everyone done with Al/Bl main-loop reads
    asm volatile("" ::: "memory");
#pragma unroll
    for (int i = 0; i < 4; ++i) {
      int row = wm * 64 + i * 16 + g * 4;            // s_loc (r=0 base, mult of 4)
#pragma unroll
      for (int j = 0; j < JF; ++j) {
        int col = wn * (BN / 2) + j * 16 + lr;       // d_loc
        float bv = bias[n0 + col];
        unsigned d0 = pack_bf2(acc[i][j][0] + bv, acc[i][j][1] + bv);
        unsigned d1 = pack_bf2(acc[i][j][2] + bv, acc[i][j][3] + bv);
        unsigned long long w = (unsigned long long)d0 | ((unsigned long long)d1 << 32);
        *reinterpret_cast<unsigned long long*>(
            &T[col * 128 + (row ^ ((col & 7) << 4))]) = w;
      }
    }
    __builtin_amdgcn_s_barrier();
    asm volatile("" ::: "memory");
    // Phase B: T -> Vtg coalesced. 128 d x 16 s-chunks(8) = 2048 chunks / 256 thr
    const int bb = m0 >> 10, s0 = m0 & 1023, h0 = n0 >> 6;
#pragma unroll
    for (int it = 0; it < 8; ++it) {
      int ch = it * 256 + tid;
      int d_loc = ch >> 4, sc = ch & 15;
      bf16x8 v = *reinterpret_cast<const bf16x8*>(
          &T[d_loc * 128 + ((sc * 8) ^ ((d_loc & 7) << 4))]);
      *reinterpret_cast<bf16x8*>(
          &Vtg[(size_t)((bb * 16 + h0 + (d_loc >> 6)) * 64 + (d_loc & 63)) * 1024
               + s0 + sc * 8]) = v;
    }
  }
}

// z=0: Q projection (+ fused V^T emit), z=1: K projection
__launch_bounds__(256)
__global__ void k_gemm_qk(const short* __restrict__ A0, const short* __restrict__ A1,
                          const short* __restrict__ Bt3,
                          const float* __restrict__ b0, const float* __restrict__ b1,
                          short* __restrict__ C0, short* __restrict__ C1,
                          short* __restrict__ Vtg) {
  if (blockIdx.z == 0)
    gemm_body<1, 128, 4096, 1024, 1024, 1>(A0, Bt3,               b0, C0, Vtg);
  else
    gemm_body<1, 128, 4096, 1024, 1024, 0>(A1, Bt3 + 1024 * 1024, b1, C1, nullptr);
}

// single GEMM: 128x64 tile -> 512 blocks (2/CU); 48KB LDS
__launch_bounds__(256)
__global__ void k_gemm_out(const short* __restrict__ A, const short* __restrict__ Bt,
                           const float* __restrict__ bias, float* __restrict__ C) {
  gemm_body<0, 64, 4096, 1024, 1024, 0>(A, Bt, bias, C, nullptr);
}

// ---------------- fused masked attention, swapped-operand flash ----------------
// (byte-identical to R9)
__launch_bounds__(512)
__global__ void k_attention(const short* __restrict__ Qp, const short* __restrict__ Kp,
                            const short* __restrict__ Vtg,
                            const unsigned long long* __restrict__ mb,
                            short* __restrict__ O) {
  __shared__ short Kl[3][64 * 64];   // [key][d], chunk-swizzled linear
  __shared__ short Vl[3][64 * 64];   // [d][key], chunk-swizzled linear
  __shared__ short Pl[8][16 * 64];   // per-wave P[q][key], chunk ^ (q&7) swizzle
  const int tid  = threadIdx.x;
  const int lane = tid & 63, wid = tid >> 6;
  const int g = lane >> 4, lr = lane & 15;
  const int g4 = 4 * g;
  const int bid = (blockIdx.x & 7) * 64 + (blockIdx.x >> 3);  // XCD swizzle
  const int qt = bid & 7, h = (bid >> 3) & 15, b = bid >> 7;
  const int qb = qt * 128 + wid * 16;
  const int srow = lane >> 3;
  const int sch  = ((lane & 7) ^ srow) * 8;

  const size_t qrow = (size_t)(b * 1024 + qb + lr);
  const float qs = 0.125f * 1.44269504088896340736f;
  bf16x8 aq[2];
#pragma unroll
  for (int db = 0; db < 2; ++db) {
    bf16x8 raw = *reinterpret_cast<const bf16x8*>(&Qp[qrow * 1024 + h * 64 + db * 32 + g * 8]);
#pragma unroll
    for (int j = 0; j < 8; j += 2) {
      unsigned pk = pack_bf2(bf2f(raw[j]) * qs, bf2f(raw[j + 1]) * qs);
      aq[db][j]     = (short)(pk & 0xffffu);
      aq[db][j + 1] = (short)(pk >> 16);
    }
  }

  const unsigned long long* mrow = &mb[qrow * 16];
  const short* Ksrc = &Kp[(size_t)(b * 1024 + wid * 8 + srow) * 1024 + h * 64 + sch];
  const short* Vsrc = &Vtg[(size_t)((b * 16 + h) * 64 + wid * 8 + srow) * 1024 + sch];

  f32x4 o[4];
#pragma unroll
  for (int d = 0; d < 4; ++d) o[d] = (f32x4){0.f, 0.f, 0.f, 0.f};
  float l_part = 0.f;
  short* Prow = &Pl[wid][lr * 64];   // this wave's q-row (lr) base

  gll16(Ksrc,                     &Kl[0][(wid * 8) * 64]);
  gll16(Vsrc,                     &Vl[0][(wid * 8) * 64]);
  gll16(Ksrc + (size_t)64 * 1024, &Kl[1][(wid * 8) * 64]);
  gll16(Vsrc + 64,                &Vl[1][(wid * 8) * 64]);
  unsigned long long mwA = mrow[0];
  unsigned long long mwB = mrow[1];
  unsigned long long mwC = 0;
  const float keep = (mwA & 1ull) ? 0.f : 1.f;   // redundant row-keep, ~mask[b,q,0]

  int cur = 0;   // kt % 3
  int b2  = 2;   // (kt+2) % 3 == (kt-1) % 3
#pragma unroll 1
  for (int kt = 0; kt < 16; ++kt) {
    if (kt >= 1) {
      const short* Vb = Vl[b2];
      __builtin_amdgcn_s_setprio(1);
#pragma unroll
      for (int kb = 0; kb < 2; ++kb) {
        bf16x8 pa = *reinterpret_cast<const bf16x8*>(
            &Prow[(((kb * 4 + g) ^ (lr & 7)) * 8)]);          // swizzled P read (2-way)
        const int cs = ((kb * 4 + g) ^ (lr & 7)) * 8;
#pragma unroll
        for (int d = 0; d < 4; ++d) {
          bf16x8 vf = *reinterpret_cast<const bf16x8*>(&Vb[(d * 16 + lr) * 64 + cs]);
          o[d] = __builtin_amdgcn_mfma_f32_16x16x32_bf16(vf, pa, o[d], 0, 0, 0);
        }
      }
      __builtin_amdgcn_s_setprio(0);
    }

    if (kt < 15) asm volatile("s_waitcnt vmcnt(4)" ::: "memory");  // stage(kt) drained
    else         asm volatile("s_waitcnt vmcnt(0)" ::: "memory");
    __builtin_amdgcn_s_barrier();
    asm volatile("" ::: "memory");

    if (kt + 2 < 16) {
      gll16(Ksrc + (size_t)(kt + 2) * 64 * 1024, &Kl[b2][(wid * 8) * 64]);
      gll16(Vsrc + (kt + 2) * 64,                &Vl[b2][(wid * 8) * 64]);
      mwC = mrow[kt + 2];                        // consumed 2 iters later
    }

    const unsigned mlo = (unsigned)mwA;
    const unsigned mhi = (unsigned)(mwA >> 32);

#pragma unroll
    for (int kc = 0; kc < 4; ++kc) {
      f32x4 a = (f32x4){0.f, 0.f, 0.f, 0.f};
      __builtin_amdgcn_s_setprio(1);
#pragma unroll
      for (int db = 0; db < 2; ++db) {
        bf16x8 kf = *reinterpret_cast<const bf16x8*>(
            &Kl[cur][(kc * 16 + lr) * 64 + (((db * 4 + g) ^ (lr & 7)) * 8)]);
        a = __builtin_amdgcn_mfma_f32_16x16x32_bf16(kf, aq[db], a, 0, 0, 0);
      }
      __builtin_amdgcn_s_setprio(0);
      const unsigned wk = ((kc < 2 ? mlo : mhi) >> (((kc & 1) << 4) + g4)) & 0xFu;
      float p0 = (wk & 1u) ? 0.f : exp2_raw(a[0]);
      float p1 = (wk & 2u) ? 0.f : exp2_raw(a[1]);
      float p2 = (wk & 4u) ? 0.f : exp2_raw(a[2]);
      float p3 = (wk & 8u) ? 0.f : exp2_raw(a[3]);
      l_part += (p0 + p1) + (p2 + p3);
      unsigned lo = pack_bf2(p0, p1), hi = pack_bf2(p2, p3);
      unsigned long long w = (unsigned long long)lo | ((unsigned long long)hi << 32);
      // keys kc*16+4g..+3 live at chunk 2kc+(g>>1), byte (g&1)*8; chunk ^= lr&7
      *reinterpret_cast<unsigned long long*>(
          &Prow[((2 * kc + (g >> 1)) ^ (lr & 7)) * 8 + (g & 1) * 4]) = w;
    }
    mwA = mwB; mwB = mwC;
    cur = (cur == 2) ? 0 : cur + 1;
    b2  = (b2  == 2) ? 0 : b2  + 1;
    asm volatile("" ::: "memory");
  }

  {  // final PV(15): V buf 15%3 == 0 (staged at kt=13, never overwritten)
    const short* Vb = Vl[0];
    __builtin_amdgcn_s_setprio(1);
#pragma unroll
    for (int kb = 0; kb < 2; ++kb) {
      bf16x8 pa = *reinterpret_cast<const bf16x8*>(
          &Prow[(((kb * 4 + g) ^ (lr & 7)) * 8)]);
      const int cs = ((kb * 4 + g) ^ (lr & 7)) * 8;
#pragma unroll
      for (int d = 0; d < 4; ++d) {
        bf16x8 vf = *reinterpret_cast<const bf16x8*>(&Vb[(d * 16 + lr) * 64 + cs]);
        o[d] = __builtin_amdgcn_mfma_f32_16x16x32_bf16(vf, pa, o[d], 0, 0, 0);
      }
    }
    __builtin_amdgcn_s_setprio(0);
  }

  float l_run = l_part;
  l_run += __shfl_xor(l_run, 16);
  l_run += __shfl_xor(l_run, 32);

  // epilogue: normalize + row-keep; stage O^T rows (d-major) into Pl, swizzled
  const float inv = (l_run > 0.f) ? keep / l_run : 0.f;
#pragma unroll
  for (int d = 0; d < 4; ++d) {
    unsigned lo = pack_bf2(o[d][0] * inv, o[d][1] * inv);
    unsigned hi = pack_bf2(o[d][2] * inv, o[d][3] * inv);
    unsigned long long w = (unsigned long long)lo | ((unsigned long long)hi << 32);
    *reinterpret_cast<unsigned long long*>(
        &Prow[((2 * d + (g >> 1)) ^ (lr & 7)) * 8 + (g & 1) * 4]) = w;
  }
#pragma unroll
  for (int it = 0; it < 2; ++it) {
    int qq = it * 8 + srow;
    bf16x8 val = *reinterpret_cast<const bf16x8*>(
        &Pl[wid][qq * 64 + (((lane & 7) ^ (qq & 7)) * 8)]);   // orig chunk = lane&7
    *reinterpret_cast<bf16x8*>(
        &O[(size_t)(b * 1024 + qt * 128 + wid * 16 + qq) * 1024 + h * 64 + (lane & 7) * 8]) = val;
  }
}

extern "C" void kernel_launch(void* const* d_in, const int* in_sizes, int n_in,
                              void* d_out, int out_size, void* d_ws, size_t ws_size,
                              hipStream_t stream) {
  const float* query  = (const float*)d_in[0];
  const float* key_in = (const float*)d_in[1];
  const void*  mask_raw = d_in[2];
  const float* Wq = (const float*)d_in[3];
  const float* bq = (const float*)d_in[4];
  const float* Wk = (const float*)d_in[5];
  const float* bk = (const float*)d_in[6];
  const float* Wp = (const float*)d_in[7];
  const float* bp = (const float*)d_in[8];

  char* ws = (char*)d_ws;
  size_t off = 0;
  auto alloc = [&](size_t bytes) {
    char* p = ws + off;
    off = (off + bytes + 255) & ~(size_t)255;
    return p;
  };
  unsigned long long* packb = (unsigned long long*)alloc(512ull << 10); // [4][1024][16] u64
  short* Qbf   = (short*)alloc(8ull << 20);
  short* Kbf   = (short*)alloc(8ull << 20);   // reused as AttnO
  short* Wt3   = (short*)alloc(6ull << 20);   // Wq^T | Wk^T | Wp^T bf16
  short* Qproj = (short*)alloc(8ull << 20);
  short* Kproj = (short*)alloc(8ull << 20);
  short* Vtg   = (short*)alloc(8ull << 20);
  short* AttnO = Kbf;

  k_prep<<<7168, 256, 0, stream>>>(query, key_in, Wq, Wk, Wp,
                                   (const unsigned*)mask_raw, Qbf, Kbf, Wt3, packb);

  dim3 gqk(8, 32, 2);  // N/128, M/128, {Q,K}
  k_gemm_qk<<<gqk, 256, 0, stream>>>(Qbf, Kbf, Wt3, bq, bk, Qproj, Kproj, Vtg);

  k_attention<<<512, 512, 0, stream>>>(Qproj, Kproj, Vtg, packb, AttnO);

  k_gemm_out<<<dim3(16, 32), 256, 0, stream>>>(AttnO, Wt3 + 2 * 1024 * 1024, bp,
                                               (float*)d_out);
}

// Round 11
// 96.962 us; speedup vs baseline: 1.1511x; 1.1511x over previous
//
#include <hip/hip_runtime.h>
#include <hip/hip_bf16.h>

using bf16x8 = __attribute__((ext_vector_type(8))) short;
using f32x4  = __attribute__((ext_vector_type(4))) float;

static __device__ __forceinline__ short f2bf(float f) {
  union { float f; unsigned u; } x; x.f = f;
  unsigned r = x.u + 0x7fffu + ((x.u >> 16) & 1u);
  return (short)(r >> 16);
}
static __device__ __forceinline__ float bf2f(short b) {
  union { unsigned u; float f; } x; x.u = ((unsigned)(unsigned short)b) << 16;
  return x.f;
}
static __device__ __forceinline__ unsigned pack_bf2(float lo, float hi) {
  __hip_bfloat162 h = __float22bfloat162_rn(float2{lo, hi});   // v_cvt_pk_bf16_f32
  unsigned u; __builtin_memcpy(&u, &h, 4); return u;
}
static __device__ __forceinline__ float exp2_raw(float x) {
  float r; asm("v_exp_f32 %0, %1" : "=v"(r) : "v"(x)); return r;  // 1 inst, no libm fixups
}
static __device__ __forceinline__ void gll16(const void* g, void* l) {
  __builtin_amdgcn_global_load_lds((__attribute__((address_space(1))) const void*)g,
                                   (__attribute__((address_space(3))) void*)l, 16, 0, 0);
}

// ---------------- fused prep: cvt q / cvt k / 3x W-transpose / mask-pack ----------------
__global__ void k_prep(const float* __restrict__ query, const float* __restrict__ key_in,
                       const float* __restrict__ Wq, const float* __restrict__ Wk,
                       const float* __restrict__ Wp,
                       const unsigned* __restrict__ mask_u32,
                       short* __restrict__ Qbf, short* __restrict__ Kbf,
                       short* __restrict__ Wt3, unsigned long long* __restrict__ packb) {
  const int bid = blockIdx.x, tid = threadIdx.x;
  if (bid < 2048) {                       // f32 -> bf16, 4M elems each
    const float* in = bid < 1024 ? query : key_in;
    short* out = bid < 1024 ? Qbf : Kbf;
    const int r = bid & 1023;
    const int n4 = (4 * 1024 * 1024) / 4;
    for (int i = r * 256 + tid; i < n4; i += 1024 * 256) {
      float4 v = reinterpret_cast<const float4*>(in)[i];
      short4 o;
      o.x = f2bf(v.x); o.y = f2bf(v.y); o.z = f2bf(v.z); o.w = f2bf(v.w);
      reinterpret_cast<short4*>(out)[i] = o;
    }
  } else if (bid < 5120) {                // W[k][n] -> bf16 Wt[n][k]
    __shared__ float tile[32][33];
    const int sub = bid - 2048;
    const int w = sub >> 10, s2 = sub & 1023;
    const int bx = s2 & 31, by = s2 >> 5;
    const float* in = w == 0 ? Wq : (w == 1 ? Wk : Wp);
    short* out = Wt3 + (size_t)w * 1024 * 1024;
    const int tx = tid & 31, ty = tid >> 5;
    int x = bx * 32 + tx, y0 = by * 32;
    for (int j = 0; j < 32; j += 8)
      tile[ty + j][tx] = in[(size_t)(y0 + ty + j) * 1024 + x];
    __syncthreads();
    int xo = by * 32 + tx, yo = bx * 32;
    for (int j = 0; j < 32; j += 8)
      out[(size_t)(yo + ty + j) * 1024 + xo] = f2bf(tile[tx][ty + j]);
  } else {                                // mask pack (dtype auto-detect)
    const int r = bid - 5120;
    unsigned probe = mask_u32[tid & 63];
    const bool u8mode = (__ballot(probe > 1u) != 0ull);
    const unsigned char* s8 = (const unsigned char*)mask_u32;
    const int* s32 = (const int*)mask_u32;
    const int n = 4 * 1024 * 1024;
    for (int e = r * 256 + tid; e < n; e += 2048 * 256) {
      int v = u8mode ? (int)s8[e] : s32[e];
      unsigned long long b = __ballot(v != 0);
      if ((tid & 63) == 0) packb[e >> 6] = b;
    }
  }
}

// ---------------- bf16 MFMA GEMM body: C = A @ Bt^T + bias ----------------
// 128xBN tile, 4 waves (2x2), BK=64, 2-buffer, early-issue stage -> compute
// -> vmcnt(0)+barrier. Conflict-free chunk^row swizzle.
// LDS is passed in from the kernel so multiple template instantiations in one
// kernel SHARE one allocation (R10 lesson: per-instantiation __shared__ doubled
// LDS to 128KB -> 1 block/CU).
// VT_OUT: emit per-head-transposed tile to Vtg[(b*16+h)*64+d][s] via T=Al (32KB).
template<int OUT_BF16, int BN, int M, int N, int K, int VT_OUT>
__device__ __forceinline__ void gemm_body(const short* __restrict__ A,
                                          const short* __restrict__ Bt,
                                          const float* __restrict__ bias,
                                          void* __restrict__ C,
                                          short* __restrict__ Vtg,
                                          short* __restrict__ Al,   // [2][128*64]
                                          short* __restrict__ Bl) { // [2][BN*64]
  constexpr int JF = BN / 32;        // N-frags per wave (wave covers BN/2 cols)
  const int tid  = threadIdx.x;
  const int lane = tid & 63, wid = tid >> 6;
  const int g = lane >> 4, lr = lane & 15;
  const int wm = wid >> 1, wn = wid & 1;
  constexpr int nbx = N / BN;
  constexpr int nwg = nbx * (M >> 7);
  const int lin = blockIdx.y * nbx + blockIdx.x;
  const int orig = (lin & 7) * (nwg >> 3) + (lin >> 3);   // XCD swizzle (nwg % 8 == 0)
  const int m0 = (orig / nbx) * 128, n0 = (orig % nbx) * BN;
  const int srow = lane >> 3;
  const int sch  = ((lane & 7) ^ srow) * 8;     // source chunk swizzle (row&7 == srow)

  f32x4 acc[4][JF];
#pragma unroll
  for (int i = 0; i < 4; ++i)
#pragma unroll
    for (int j = 0; j < JF; ++j) acc[i][j] = (f32x4){0.f, 0.f, 0.f, 0.f};

  constexpr int NT = K >> 6;
  auto stage = [&](int buf, int kt) {
#pragma unroll
    for (int s = 0; s < 4; ++s)
      gll16(&A[(size_t)(m0 + s * 32 + wid * 8 + srow) * K + kt + sch],
            &Al[buf * 128 * 64 + (s * 32 + wid * 8) * 64]);
#pragma unroll
    for (int s = 0; s < BN / 32; ++s)
      gll16(&Bt[(size_t)(n0 + s * 32 + wid * 8 + srow) * K + kt + sch],
            &Bl[buf * BN * 64 + (s * 32 + wid * 8) * 64]);
  };

  stage(0, 0);
  asm volatile("s_waitcnt vmcnt(0)" ::: "memory");
  __builtin_amdgcn_s_barrier();
  asm volatile("" ::: "memory");

#pragma unroll 1
  for (int t = 0; t < NT; ++t) {
    const int cur = t & 1;
    if (t + 1 < NT) stage(cur ^ 1, (t + 1) * 64);   // readers of that buf done last iter
#pragma unroll
    for (int kb = 0; kb < 2; ++kb) {
      const int cs = ((kb * 4 + g) ^ (lr & 7)) * 8;      // swizzled read chunk
      bf16x8 af[4], bfr[JF];
#pragma unroll
      for (int i = 0; i < 4; ++i)
        af[i] = *reinterpret_cast<const bf16x8*>(
            &Al[cur * 128 * 64 + (wm * 64 + i * 16 + lr) * 64 + cs]);
#pragma unroll
      for (int j = 0; j < JF; ++j)
        bfr[j] = *reinterpret_cast<const bf16x8*>(
            &Bl[cur * BN * 64 + (wn * (BN / 2) + j * 16 + lr) * 64 + cs]);
#pragma unroll
      for (int i = 0; i < 4; ++i)
#pragma unroll
        for (int j = 0; j < JF; ++j)
          acc[i][j] = __builtin_amdgcn_mfma_f32_16x16x32_bf16(af[i], bfr[j], acc[i][j], 0, 0, 0);
    }
    if (t + 1 < NT) {
      asm volatile("s_waitcnt vmcnt(0)" ::: "memory");  // stage(t+1) complete (had full flight)
      __builtin_amdgcn_s_barrier();                     // + everyone done reading cur
      asm volatile("" ::: "memory");
    }
  }

  // C store
#pragma unroll
  for (int i = 0; i < 4; ++i) {
    int row = m0 + wm * 64 + i * 16 + g * 4;
#pragma unroll
    for (int j = 0; j < JF; ++j) {
      int col = n0 + wn * (BN / 2) + j * 16 + lr;
      float bv = bias[col];
#pragma unroll
      for (int r = 0; r < 4; ++r) {
        float v = acc[i][j][r] + bv;
        if (OUT_BF16) ((short*)C)[(size_t)(row + r) * N + col] = f2bf(v);
        else          ((float*)C)[(size_t)(row + r) * N + col] = v;
      }
    }
  }

  if (VT_OUT) {
    // Phase A: frags -> T LDS, layout T[d_loc][s_loc ^ ((d_loc&7)<<4)] over Al (32KB)
    short* T = Al;
    __builtin_amdgcn_s_barrier();   // all waves past their last LDS reads
    asm volatile("" ::: "memory");
#pragma unroll
    for (int i = 0; i < 4; ++i) {
      int row = wm * 64 + i * 16 + g * 4;            // s_loc (r=0 base, mult of 4)
#pragma unroll
      for (int j = 0; j < JF; ++j) {
        int col = wn * (BN / 2) + j * 16 + lr;       // d_loc
        float bv = bias[n0 + col];
        unsigned d0 = pack_bf2(acc[i][j][0] + bv, acc[i][j][1] + bv);
        unsigned d1 = pack_bf2(acc[i][j][2] + bv, acc[i][j][3] + bv);
        unsigned long long w = (unsigned long long)d0 | ((unsigned long long)d1 << 32);
        *reinterpret_cast<unsigned long long*>(
            &T[col * 128 + (row ^ ((col & 7) << 4))]) = w;
      }
    }
    __builtin_amdgcn_s_barrier();
    asm volatile("" ::: "memory");
    // Phase B: T -> Vtg coalesced. 128 d x 16 s-chunks(8) = 2048 chunks / 256 thr
    const int bb = m0 >> 10, s0 = m0 & 1023, h0 = n0 >> 6;
#pragma unroll
    for (int it = 0; it < 8; ++it) {
      int ch = it * 256 + tid;
      int d_loc = ch >> 4, sc = ch & 15;
      bf16x8 v = *reinterpret_cast<const bf16x8*>(
          &T[d_loc * 128 + ((sc * 8) ^ ((d_loc & 7) << 4))]);
      *reinterpret_cast<bf16x8*>(
          &Vtg[(size_t)((bb * 16 + h0 + (d_loc >> 6)) * 64 + (d_loc & 63)) * 1024
               + s0 + sc * 8]) = v;
    }
  }
}

// z=0: Q projection (+ fused V^T emit), z=1: K projection. Shared 64KB LDS.
__launch_bounds__(256)
__global__ void k_gemm_qk(const short* __restrict__ A0, const short* __restrict__ A1,
                          const short* __restrict__ Bt3,
                          const float* __restrict__ b0, const float* __restrict__ b1,
                          short* __restrict__ C0, short* __restrict__ C1,
                          short* __restrict__ Vtg) {
  __shared__ short Al[2][128 * 64];
  __shared__ short Bl[2][128 * 64];
  if (blockIdx.z == 0)
    gemm_body<1, 128, 4096, 1024, 1024, 1>(A0, Bt3, b0, C0, Vtg,
                                           &Al[0][0], &Bl[0][0]);
  else
    gemm_body<1, 128, 4096, 1024, 1024, 0>(A1, Bt3 + 1024 * 1024, b1, C1, nullptr,
                                           &Al[0][0], &Bl[0][0]);
}

// single GEMM: 128x64 tile -> 512 blocks (2/CU); 48KB LDS
__launch_bounds__(256)
__global__ void k_gemm_out(const short* __restrict__ A, const short* __restrict__ Bt,
                           const float* __restrict__ bias, float* __restrict__ C) {
  __shared__ short Al[2][128 * 64];
  __shared__ short Bl[2][64 * 64];
  gemm_body<0, 64, 4096, 1024, 1024, 0>(A, Bt, bias, C, nullptr,
                                        &Al[0][0], &Bl[0][0]);
}

// ---------------- fused masked attention, swapped-operand flash ----------------
// (byte-identical to R9)
__launch_bounds__(512)
__global__ void k_attention(const short* __restrict__ Qp, const short* __restrict__ Kp,
                            const short* __restrict__ Vtg,
                            const unsigned long long* __restrict__ mb,
                            short* __restrict__ O) {
  __shared__ short Kl[3][64 * 64];   // [key][d], chunk-swizzled linear
  __shared__ short Vl[3][64 * 64];   // [d][key], chunk-swizzled linear
  __shared__ short Pl[8][16 * 64];   // per-wave P[q][key], chunk ^ (q&7) swizzle
  const int tid  = threadIdx.x;
  const int lane = tid & 63, wid = tid >> 6;
  const int g = lane >> 4, lr = lane & 15;
  const int g4 = 4 * g;
  const int bid = (blockIdx.x & 7) * 64 + (blockIdx.x >> 3);  // XCD swizzle
  const int qt = bid & 7, h = (bid >> 3) & 15, b = bid >> 7;
  const int qb = qt * 128 + wid * 16;
  const int srow = lane >> 3;
  const int sch  = ((lane & 7) ^ srow) * 8;

  const size_t qrow = (size_t)(b * 1024 + qb + lr);
  const float qs = 0.125f * 1.44269504088896340736f;
  bf16x8 aq[2];
#pragma unroll
  for (int db = 0; db < 2; ++db) {
    bf16x8 raw = *reinterpret_cast<const bf16x8*>(&Qp[qrow * 1024 + h * 64 + db * 32 + g * 8]);
#pragma unroll
    for (int j = 0; j < 8; j += 2) {
      unsigned pk = pack_bf2(bf2f(raw[j]) * qs, bf2f(raw[j + 1]) * qs);
      aq[db][j]     = (short)(pk & 0xffffu);
      aq[db][j + 1] = (short)(pk >> 16);
    }
  }

  const unsigned long long* mrow = &mb[qrow * 16];
  const short* Ksrc = &Kp[(size_t)(b * 1024 + wid * 8 + srow) * 1024 + h * 64 + sch];
  const short* Vsrc = &Vtg[(size_t)((b * 16 + h) * 64 + wid * 8 + srow) * 1024 + sch];

  f32x4 o[4];
#pragma unroll
  for (int d = 0; d < 4; ++d) o[d] = (f32x4){0.f, 0.f, 0.f, 0.f};
  float l_part = 0.f;
  short* Prow = &Pl[wid][lr * 64];   // this wave's q-row (lr) base

  gll16(Ksrc,                     &Kl[0][(wid * 8) * 64]);
  gll16(Vsrc,                     &Vl[0][(wid * 8) * 64]);
  gll16(Ksrc + (size_t)64 * 1024, &Kl[1][(wid * 8) * 64]);
  gll16(Vsrc + 64,                &Vl[1][(wid * 8) * 64]);
  unsigned long long mwA = mrow[0];
  unsigned long long mwB = mrow[1];
  unsigned long long mwC = 0;
  const float keep = (mwA & 1ull) ? 0.f : 1.f;   // redundant row-keep, ~mask[b,q,0]

  int cur = 0;   // kt % 3
  int b2  = 2;   // (kt+2) % 3 == (kt-1) % 3
#pragma unroll 1
  for (int kt = 0; kt < 16; ++kt) {
    if (kt >= 1) {
      const short* Vb = Vl[b2];
      __builtin_amdgcn_s_setprio(1);
#pragma unroll
      for (int kb = 0; kb < 2; ++kb) {
        bf16x8 pa = *reinterpret_cast<const bf16x8*>(
            &Prow[(((kb * 4 + g) ^ (lr & 7)) * 8)]);          // swizzled P read (2-way)
        const int cs = ((kb * 4 + g) ^ (lr & 7)) * 8;
#pragma unroll
        for (int d = 0; d < 4; ++d) {
          bf16x8 vf = *reinterpret_cast<const bf16x8*>(&Vb[(d * 16 + lr) * 64 + cs]);
          o[d] = __builtin_amdgcn_mfma_f32_16x16x32_bf16(vf, pa, o[d], 0, 0, 0);
        }
      }
      __builtin_amdgcn_s_setprio(0);
    }

    if (kt < 15) asm volatile("s_waitcnt vmcnt(4)" ::: "memory");  // stage(kt) drained
    else         asm volatile("s_waitcnt vmcnt(0)" ::: "memory");
    __builtin_amdgcn_s_barrier();
    asm volatile("" ::: "memory");

    if (kt + 2 < 16) {
      gll16(Ksrc + (size_t)(kt + 2) * 64 * 1024, &Kl[b2][(wid * 8) * 64]);
      gll16(Vsrc + (kt + 2) * 64,                &Vl[b2][(wid * 8) * 64]);
      mwC = mrow[kt + 2];                        // consumed 2 iters later
    }

    const unsigned mlo = (unsigned)mwA;
    const unsigned mhi = (unsigned)(mwA >> 32);

#pragma unroll
    for (int kc = 0; kc < 4; ++kc) {
      f32x4 a = (f32x4){0.f, 0.f, 0.f, 0.f};
      __builtin_amdgcn_s_setprio(1);
#pragma unroll
      for (int db = 0; db < 2; ++db) {
        bf16x8 kf = *reinterpret_cast<const bf16x8*>(
            &Kl[cur][(kc * 16 + lr) * 64 + (((db * 4 + g) ^ (lr & 7)) * 8)]);
        a = __builtin_amdgcn_mfma_f32_16x16x32_bf16(kf, aq[db], a, 0, 0, 0);
      }
      __builtin_amdgcn_s_setprio(0);
      const unsigned wk = ((kc < 2 ? mlo : mhi) >> (((kc & 1) << 4) + g4)) & 0xFu;
      float p0 = (wk & 1u) ? 0.f : exp2_raw(a[0]);
      float p1 = (wk & 2u) ? 0.f : exp2_raw(a[1]);
      float p2 = (wk & 4u) ? 0.f : exp2_raw(a[2]);
      float p3 = (wk & 8u) ? 0.f : exp2_raw(a[3]);
      l_part += (p0 + p1) + (p2 + p3);
      unsigned lo = pack_bf2(p0, p1), hi = pack_bf2(p2, p3);
      unsigned long long w = (unsigned long long)lo | ((unsigned long long)hi << 32);
      // keys kc*16+4g..+3 live at chunk 2kc+(g>>1), byte (g&1)*8; chunk ^= lr&7
      *reinterpret_cast<unsigned long long*>(
          &Prow[((2 * kc + (g >> 1)) ^ (lr & 7)) * 8 + (g & 1) * 4]) = w;
    }
    mwA = mwB; mwB = mwC;
    cur = (cur == 2) ? 0 : cur + 1;
    b2  = (b2  == 2) ? 0 : b2  + 1;
    asm volatile("" ::: "memory");
  }

  {  // final PV(15): V buf 15%3 == 0 (staged at kt=13, never overwritten)
    const short* Vb = Vl[0];
    __builtin_amdgcn_s_setprio(1);
#pragma unroll
    for (int kb = 0; kb < 2; ++kb) {
      bf16x8 pa = *reinterpret_cast<const bf16x8*>(
          &Prow[(((kb * 4 + g) ^ (lr & 7)) * 8)]);
      const int cs = ((kb * 4 + g) ^ (lr & 7)) * 8;
#pragma unroll
      for (int d = 0; d < 4; ++d) {
        bf16x8 vf = *reinterpret_cast<const bf16x8*>(&Vb[(d * 16 + lr) * 64 + cs]);
        o[d] = __builtin_amdgcn_mfma_f32_16x16x32_bf16(vf, pa, o[d], 0, 0, 0);
      }
    }
    __builtin_amdgcn_s_setprio(0);
  }

  float l_run = l_part;
  l_run += __shfl_xor(l_run, 16);
  l_run += __shfl_xor(l_run, 32);

  // epilogue: normalize + row-keep; stage O^T rows (d-major) into Pl, swizzled
  const float inv = (l_run > 0.f) ? keep / l_run : 0.f;
#pragma unroll
  for (int d = 0; d < 4; ++d) {
    unsigned lo = pack_bf2(o[d][0] * inv, o[d][1] * inv);
    unsigned hi = pack_bf2(o[d][2] * inv, o[d][3] * inv);
    unsigned long long w = (unsigned long long)lo | ((unsigned long long)hi << 32);
    *reinterpret_cast<unsigned long long*>(
        &Prow[((2 * d + (g >> 1)) ^ (lr & 7)) * 8 + (g & 1) * 4]) = w;
  }
#pragma unroll
  for (int it = 0; it < 2; ++it) {
    int qq = it * 8 + srow;
    bf16x8 val = *reinterpret_cast<const bf16x8*>(
        &Pl[wid][qq * 64 + (((lane & 7) ^ (qq & 7)) * 8)]);   // orig chunk = lane&7
    *reinterpret_cast<bf16x8*>(
        &O[(size_t)(b * 1024 + qt * 128 + wid * 16 + qq) * 1024 + h * 64 + (lane & 7) * 8]) = val;
  }
}

extern "C" void kernel_launch(void* const* d_in, const int* in_sizes, int n_in,
                              void* d_out, int out_size, void* d_ws, size_t ws_size,
                              hipStream_t stream) {
  const float* query  = (const float*)d_in[0];
  const float* key_in = (const float*)d_in[1];
  const void*  mask_raw = d_in[2];
  const float* Wq = (const float*)d_in[3];
  const float* bq = (const float*)d_in[4];
  const float* Wk = (const float*)d_in[5];
  const float* bk = (const float*)d_in[6];
  const float* Wp = (const float*)d_in[7];
  const float* bp = (const float*)d_in[8];

  char* ws = (char*)d_ws;
  size_t off = 0;
  auto alloc = [&](size_t bytes) {
    char* p = ws + off;
    off = (off + bytes + 255) & ~(size_t)255;
    return p;
  };
  unsigned long long* packb = (unsigned long long*)alloc(512ull << 10); // [4][1024][16] u64
  short* Qbf   = (short*)alloc(8ull << 20);
  short* Kbf   = (short*)alloc(8ull << 20);   // reused as AttnO
  short* Wt3   = (short*)alloc(6ull << 20);   // Wq^T | Wk^T | Wp^T bf16
  short* Qproj = (short*)alloc(8ull << 20);
  short* Kproj = (short*)alloc(8ull << 20);
  short* Vtg   = (short*)alloc(8ull << 20);
  short* AttnO = Kbf;

  k_prep<<<7168, 256, 0, stream>>>(query, key_in, Wq, Wk, Wp,
                                   (const unsigned*)mask_raw, Qbf, Kbf, Wt3, packb);

  dim3 gqk(8, 32, 2);  // N/128, M/128, {Q,K}
  k_gemm_qk<<<gqk, 256, 0, stream>>>(Qbf, Kbf, Wt3, bq, bk, Qproj, Kproj, Vtg);

  k_attention<<<512, 512, 0, stream>>>(Qproj, Kproj, Vtg, packb, AttnO);

  k_gemm_out<<<dim3(16, 32), 256, 0, stream>>>(AttnO, Wt3 + 2 * 1024 * 1024, bp,
                                               (float*)d_out);
}

// Round 12
// 93.320 us; speedup vs baseline: 1.1961x; 1.0390x over previous
//
#include <hip/hip_runtime.h>
#include <hip/hip_bf16.h>

using bf16x8 = __attribute__((ext_vector_type(8))) short;
using f32x4  = __attribute__((ext_vector_type(4))) float;

static __device__ __forceinline__ short f2bf(float f) {
  union { float f; unsigned u; } x; x.f = f;
  unsigned r = x.u + 0x7fffu + ((x.u >> 16) & 1u);
  return (short)(r >> 16);
}
static __device__ __forceinline__ float bf2f(short b) {
  union { unsigned u; float f; } x; x.u = ((unsigned)(unsigned short)b) << 16;
  return x.f;
}
static __device__ __forceinline__ unsigned pack_bf2(float lo, float hi) {
  __hip_bfloat162 h = __float22bfloat162_rn(float2{lo, hi});   // v_cvt_pk_bf16_f32
  unsigned u; __builtin_memcpy(&u, &h, 4); return u;
}
static __device__ __forceinline__ float exp2_raw(float x) {
  float r; asm("v_exp_f32 %0, %1" : "=v"(r) : "v"(x)); return r;  // 1 inst, no libm fixups
}
static __device__ __forceinline__ void gll16(const void* g, void* l) {
  __builtin_amdgcn_global_load_lds((__attribute__((address_space(1))) const void*)g,
                                   (__attribute__((address_space(3))) void*)l, 16, 0, 0);
}

// ---------------- fused prep: cvt q / cvt k / 3x W-transpose / mask-pack ----------------
__global__ void k_prep(const float* __restrict__ query, const float* __restrict__ key_in,
                       const float* __restrict__ Wq, const float* __restrict__ Wk,
                       const float* __restrict__ Wp,
                       const unsigned* __restrict__ mask_u32,
                       short* __restrict__ Qbf, short* __restrict__ Kbf,
                       short* __restrict__ Wt3, unsigned long long* __restrict__ packb) {
  const int bid = blockIdx.x, tid = threadIdx.x;
  if (bid < 2048) {                       // f32 -> bf16, 4M elems each
    const float* in = bid < 1024 ? query : key_in;
    short* out = bid < 1024 ? Qbf : Kbf;
    const int r = bid & 1023;
    const int n4 = (4 * 1024 * 1024) / 4;
    for (int i = r * 256 + tid; i < n4; i += 1024 * 256) {
      float4 v = reinterpret_cast<const float4*>(in)[i];
      short4 o;
      o.x = f2bf(v.x); o.y = f2bf(v.y); o.z = f2bf(v.z); o.w = f2bf(v.w);
      reinterpret_cast<short4*>(out)[i] = o;
    }
  } else if (bid < 5120) {                // W[k][n] -> bf16 Wt[n][k]
    __shared__ float tile[32][33];
    const int sub = bid - 2048;
    const int w = sub >> 10, s2 = sub & 1023;
    const int bx = s2 & 31, by = s2 >> 5;
    const float* in = w == 0 ? Wq : (w == 1 ? Wk : Wp);
    short* out = Wt3 + (size_t)w * 1024 * 1024;
    const int tx = tid & 31, ty = tid >> 5;
    int x = bx * 32 + tx, y0 = by * 32;
    for (int j = 0; j < 32; j += 8)
      tile[ty + j][tx] = in[(size_t)(y0 + ty + j) * 1024 + x];
    __syncthreads();
    int xo = by * 32 + tx, yo = bx * 32;
    for (int j = 0; j < 32; j += 8)
      out[(size_t)(yo + ty + j) * 1024 + xo] = f2bf(tile[tx][ty + j]);
  } else {                                // mask pack (dtype auto-detect)
    const int r = bid - 5120;
    unsigned probe = mask_u32[tid & 63];
    const bool u8mode = (__ballot(probe > 1u) != 0ull);
    const unsigned char* s8 = (const unsigned char*)mask_u32;
    const int* s32 = (const int*)mask_u32;
    const int n = 4 * 1024 * 1024;
    for (int e = r * 256 + tid; e < n; e += 2048 * 256) {
      int v = u8mode ? (int)s8[e] : s32[e];
      unsigned long long b = __ballot(v != 0);
      if ((tid & 63) == 0) packb[e >> 6] = b;
    }
  }
}

// ---------------- bf16 MFMA GEMM body (as R11) ----------------
template<int OUT_BF16, int BN, int M, int N, int K, int VT_OUT>
__device__ __forceinline__ void gemm_body(const short* __restrict__ A,
                                          const short* __restrict__ Bt,
                                          const float* __restrict__ bias,
                                          void* __restrict__ C,
                                          short* __restrict__ Vtg,
                                          short* __restrict__ Al,   // [2][128*64]
                                          short* __restrict__ Bl) { // [2][BN*64]
  constexpr int JF = BN / 32;
  const int tid  = threadIdx.x;
  const int lane = tid & 63, wid = tid >> 6;
  const int g = lane >> 4, lr = lane & 15;
  const int wm = wid >> 1, wn = wid & 1;
  constexpr int nbx = N / BN;
  constexpr int nwg = nbx * (M >> 7);
  const int lin = blockIdx.y * nbx + blockIdx.x;
  const int orig = (lin & 7) * (nwg >> 3) + (lin >> 3);   // XCD swizzle (nwg % 8 == 0)
  const int m0 = (orig / nbx) * 128, n0 = (orig % nbx) * BN;
  const int srow = lane >> 3;
  const int sch  = ((lane & 7) ^ srow) * 8;

  f32x4 acc[4][JF];
#pragma unroll
  for (int i = 0; i < 4; ++i)
#pragma unroll
    for (int j = 0; j < JF; ++j) acc[i][j] = (f32x4){0.f, 0.f, 0.f, 0.f};

  constexpr int NT = K >> 6;
  auto stage = [&](int buf, int kt) {
#pragma unroll
    for (int s = 0; s < 4; ++s)
      gll16(&A[(size_t)(m0 + s * 32 + wid * 8 + srow) * K + kt + sch],
            &Al[buf * 128 * 64 + (s * 32 + wid * 8) * 64]);
#pragma unroll
    for (int s = 0; s < BN / 32; ++s)
      gll16(&Bt[(size_t)(n0 + s * 32 + wid * 8 + srow) * K + kt + sch],
            &Bl[buf * BN * 64 + (s * 32 + wid * 8) * 64]);
  };

  stage(0, 0);
  asm volatile("s_waitcnt vmcnt(0)" ::: "memory");
  __builtin_amdgcn_s_barrier();
  asm volatile("" ::: "memory");

#pragma unroll 1
  for (int t = 0; t < NT; ++t) {
    const int cur = t & 1;
    if (t + 1 < NT) stage(cur ^ 1, (t + 1) * 64);
#pragma unroll
    for (int kb = 0; kb < 2; ++kb) {
      const int cs = ((kb * 4 + g) ^ (lr & 7)) * 8;
      bf16x8 af[4], bfr[JF];
#pragma unroll
      for (int i = 0; i < 4; ++i)
        af[i] = *reinterpret_cast<const bf16x8*>(
            &Al[cur * 128 * 64 + (wm * 64 + i * 16 + lr) * 64 + cs]);
#pragma unroll
      for (int j = 0; j < JF; ++j)
        bfr[j] = *reinterpret_cast<const bf16x8*>(
            &Bl[cur * BN * 64 + (wn * (BN / 2) + j * 16 + lr) * 64 + cs]);
#pragma unroll
      for (int i = 0; i < 4; ++i)
#pragma unroll
        for (int j = 0; j < JF; ++j)
          acc[i][j] = __builtin_amdgcn_mfma_f32_16x16x32_bf16(af[i], bfr[j], acc[i][j], 0, 0, 0);
    }
    if (t + 1 < NT) {
      asm volatile("s_waitcnt vmcnt(0)" ::: "memory");
      __builtin_amdgcn_s_barrier();
      asm volatile("" ::: "memory");
    }
  }

#pragma unroll
  for (int i = 0; i < 4; ++i) {
    int row = m0 + wm * 64 + i * 16 + g * 4;
#pragma unroll
    for (int j = 0; j < JF; ++j) {
      int col = n0 + wn * (BN / 2) + j * 16 + lr;
      float bv = bias[col];
#pragma unroll
      for (int r = 0; r < 4; ++r) {
        float v = acc[i][j][r] + bv;
        if (OUT_BF16) ((short*)C)[(size_t)(row + r) * N + col] = f2bf(v);
        else          ((float*)C)[(size_t)(row + r) * N + col] = v;
      }
    }
  }

  if (VT_OUT) {
    short* T = Al;
    __builtin_amdgcn_s_barrier();
    asm volatile("" ::: "memory");
#pragma unroll
    for (int i = 0; i < 4; ++i) {
      int row = wm * 64 + i * 16 + g * 4;
#pragma unroll
      for (int j = 0; j < JF; ++j) {
        int col = wn * (BN / 2) + j * 16 + lr;
        float bv = bias[n0 + col];
        unsigned d0 = pack_bf2(acc[i][j][0] + bv, acc[i][j][1] + bv);
        unsigned d1 = pack_bf2(acc[i][j][2] + bv, acc[i][j][3] + bv);
        unsigned long long w = (unsigned long long)d0 | ((unsigned long long)d1 << 32);
        *reinterpret_cast<unsigned long long*>(
            &T[col * 128 + (row ^ ((col & 7) << 4))]) = w;
      }
    }
    __builtin_amdgcn_s_barrier();
    asm volatile("" ::: "memory");
    const int bb = m0 >> 10, s0 = m0 & 1023, h0 = n0 >> 6;
#pragma unroll
    for (int it = 0; it < 8; ++it) {
      int ch = it * 256 + tid;
      int d_loc = ch >> 4, sc = ch & 15;
      bf16x8 v = *reinterpret_cast<const bf16x8*>(
          &T[d_loc * 128 + ((sc * 8) ^ ((d_loc & 7) << 4))]);
      *reinterpret_cast<bf16x8*>(
          &Vtg[(size_t)((bb * 16 + h0 + (d_loc >> 6)) * 64 + (d_loc & 63)) * 1024
               + s0 + sc * 8]) = v;
    }
  }
}

__launch_bounds__(256)
__global__ void k_gemm_qk(const short* __restrict__ A0, const short* __restrict__ A1,
                          const short* __restrict__ Bt3,
                          const float* __restrict__ b0, const float* __restrict__ b1,
                          short* __restrict__ C0, short* __restrict__ C1,
                          short* __restrict__ Vtg) {
  __shared__ short Al[2][128 * 64];
  __shared__ short Bl[2][128 * 64];
  if (blockIdx.z == 0)
    gemm_body<1, 128, 4096, 1024, 1024, 1>(A0, Bt3, b0, C0, Vtg,
                                           &Al[0][0], &Bl[0][0]);
  else
    gemm_body<1, 128, 4096, 1024, 1024, 0>(A1, Bt3 + 1024 * 1024, b1, C1, nullptr,
                                           &Al[0][0], &Bl[0][0]);
}

__launch_bounds__(256)
__global__ void k_gemm_out(const short* __restrict__ A, const short* __restrict__ Bt,
                           const float* __restrict__ bias, float* __restrict__ C) {
  __shared__ short Al[2][128 * 64];
  __shared__ short Bl[2][64 * 64];
  gemm_body<0, 64, 4096, 1024, 1024, 0>(A, Bt, bias, C, nullptr,
                                        &Al[0][0], &Bl[0][0]);
}

// ---------------- fused masked attention, swapped-operand flash ----------------
// KVBLK=128: 8 iterations x 128 keys (two 64-key sub-tiles, per-half code reused
// verbatim), ONE barrier per iteration (was 16). 2-buffer K/V, masks rotated
// 2-deep. LDS = 32K(K) + 32K(V) + 16K(P) = 80KB -> 2 blocks/CU (160KiB exact).
// vmcnt ledger, iter kt issue order: [wait|barrier|stage(kt+1)=4 gll16 + 2 mask
// loads|compute]. Top of iter kt: drain stage(kt) (4, issued iter kt-1), newer =
// 2 mask(kt) loads -> vmcnt(2). Compiler's own wait before mask use leaves
// stage(kt+1) in flight. Last iter: vmcnt(0).
__launch_bounds__(512)
__global__ void k_attention(const short* __restrict__ Qp, const short* __restrict__ Kp,
                            const short* __restrict__ Vtg,
                            const unsigned long long* __restrict__ mb,
                            short* __restrict__ O) {
  __shared__ short Kl[2][2][64 * 64];   // [buf][half][key][d], chunk-swizzled
  __shared__ short Vl[2][2][64 * 64];   // [buf][half][d][key], chunk-swizzled
  __shared__ short Pl[8][16 * 64];      // per-wave P[q][key], chunk ^ (q&7) swizzle
  const int tid  = threadIdx.x;
  const int lane = tid & 63, wid = tid >> 6;
  const int g = lane >> 4, lr = lane & 15;
  const int g4 = 4 * g;
  const int bid = (blockIdx.x & 7) * 64 + (blockIdx.x >> 3);  // XCD swizzle
  const int qt = bid & 7, h = (bid >> 3) & 15, b = bid >> 7;
  const int qb = qt * 128 + wid * 16;
  const int srow = lane >> 3;
  const int sch  = ((lane & 7) ^ srow) * 8;

  const size_t qrow = (size_t)(b * 1024 + qb + lr);
  const float qs = 0.125f * 1.44269504088896340736f;
  bf16x8 aq[2];
#pragma unroll
  for (int db = 0; db < 2; ++db) {
    bf16x8 raw = *reinterpret_cast<const bf16x8*>(&Qp[qrow * 1024 + h * 64 + db * 32 + g * 8]);
#pragma unroll
    for (int j = 0; j < 8; j += 2) {
      unsigned pk = pack_bf2(bf2f(raw[j]) * qs, bf2f(raw[j + 1]) * qs);
      aq[db][j]     = (short)(pk & 0xffffu);
      aq[db][j + 1] = (short)(pk >> 16);
    }
  }

  const unsigned long long* mrow = &mb[qrow * 16];
  const short* Ksrc = &Kp[(size_t)(b * 1024 + wid * 8 + srow) * 1024 + h * 64 + sch];
  const short* Vsrc = &Vtg[(size_t)((b * 16 + h) * 64 + wid * 8 + srow) * 1024 + sch];

  f32x4 o[4];
#pragma unroll
  for (int d = 0; d < 4; ++d) o[d] = (f32x4){0.f, 0.f, 0.f, 0.f};
  float l_part = 0.f;
  short* Prow = &Pl[wid][lr * 64];

  // prologue: stage tile 0 (both halves)
  gll16(Ksrc,                           &Kl[0][0][(wid * 8) * 64]);
  gll16(Ksrc + (size_t)64 * 1024,       &Kl[0][1][(wid * 8) * 64]);
  gll16(Vsrc,                           &Vl[0][0][(wid * 8) * 64]);
  gll16(Vsrc + 64,                      &Vl[0][1][(wid * 8) * 64]);
  unsigned long long mwA0 = mrow[0], mwA1 = mrow[1];
  unsigned long long mwB0 = 0, mwB1 = 0;
  const float keep = (mwA0 & 1ull) ? 0.f : 1.f;   // redundant row-keep, ~mask[b,q,0]

#pragma unroll 1
  for (int kt = 0; kt < 8; ++kt) {
    const int cur = kt & 1;
    if (kt < 7) asm volatile("s_waitcnt vmcnt(2)" ::: "memory");  // stage(kt) drained
    else        asm volatile("s_waitcnt vmcnt(0)" ::: "memory");
    __builtin_amdgcn_s_barrier();
    asm volatile("" ::: "memory");

    if (kt + 1 < 8) {   // stage(kt+1) into buf cur^1 (its readers finished last iter)
      const size_t kb128 = (size_t)(kt + 1) * 128;
      gll16(Ksrc + kb128 * 1024,              &Kl[cur ^ 1][0][(wid * 8) * 64]);
      gll16(Ksrc + (kb128 + 64) * 1024,       &Kl[cur ^ 1][1][(wid * 8) * 64]);
      gll16(Vsrc + kb128,                     &Vl[cur ^ 1][0][(wid * 8) * 64]);
      gll16(Vsrc + kb128 + 64,                &Vl[cur ^ 1][1][(wid * 8) * 64]);
      mwB0 = mrow[2 * kt + 2];
      mwB1 = mrow[2 * kt + 3];
    }

#pragma unroll
    for (int hk = 0; hk < 2; ++hk) {
      const unsigned long long mwfull = hk ? mwA1 : mwA0;
      const unsigned mlo = (unsigned)mwfull;
      const unsigned mhi = (unsigned)(mwfull >> 32);
      const short* Kb = Kl[cur][hk];
      const short* Vb = Vl[cur][hk];

      // S^T = K * Q^T (exp2 domain); frag kc -> keys kc*16 + 4g + r, q = lr
#pragma unroll
      for (int kc = 0; kc < 4; ++kc) {
        f32x4 a = (f32x4){0.f, 0.f, 0.f, 0.f};
        __builtin_amdgcn_s_setprio(1);
#pragma unroll
        for (int db = 0; db < 2; ++db) {
          bf16x8 kf = *reinterpret_cast<const bf16x8*>(
              &Kb[(kc * 16 + lr) * 64 + (((db * 4 + g) ^ (lr & 7)) * 8)]);
          a = __builtin_amdgcn_mfma_f32_16x16x32_bf16(kf, aq[db], a, 0, 0, 0);
        }
        __builtin_amdgcn_s_setprio(0);
        const unsigned wk = ((kc < 2 ? mlo : mhi) >> (((kc & 1) << 4) + g4)) & 0xFu;
        float p0 = (wk & 1u) ? 0.f : exp2_raw(a[0]);
        float p1 = (wk & 2u) ? 0.f : exp2_raw(a[1]);
        float p2 = (wk & 4u) ? 0.f : exp2_raw(a[2]);
        float p3 = (wk & 8u) ? 0.f : exp2_raw(a[3]);
        l_part += (p0 + p1) + (p2 + p3);
        unsigned lo = pack_bf2(p0, p1), hi = pack_bf2(p2, p3);
        unsigned long long w = (unsigned long long)lo | ((unsigned long long)hi << 32);
        *reinterpret_cast<unsigned long long*>(
            &Prow[((2 * kc + (g >> 1)) ^ (lr & 7)) * 8 + (g & 1) * 4]) = w;
      }

      // PV half: O^T += V^T * P^T  (same-wave LDS W->R ordered by lgkmcnt)
      __builtin_amdgcn_s_setprio(1);
#pragma unroll
      for (int kb = 0; kb < 2; ++kb) {
        bf16x8 pa = *reinterpret_cast<const bf16x8*>(
            &Prow[(((kb * 4 + g) ^ (lr & 7)) * 8)]);
        const int cs = ((kb * 4 + g) ^ (lr & 7)) * 8;
#pragma unroll
        for (int d = 0; d < 4; ++d) {
          bf16x8 vf = *reinterpret_cast<const bf16x8*>(&Vb[(d * 16 + lr) * 64 + cs]);
          o[d] = __builtin_amdgcn_mfma_f32_16x16x32_bf16(vf, pa, o[d], 0, 0, 0);
        }
      }
      __builtin_amdgcn_s_setprio(0);
    }
    mwA0 = mwB0; mwA1 = mwB1;
    asm volatile("" ::: "memory");
  }

  float l_run = l_part;
  l_run += __shfl_xor(l_run, 16);
  l_run += __shfl_xor(l_run, 32);

  // epilogue: normalize + row-keep; stage O^T rows (d-major) into Pl, swizzled
  const float inv = (l_run > 0.f) ? keep / l_run : 0.f;
#pragma unroll
  for (int d = 0; d < 4; ++d) {
    unsigned lo = pack_bf2(o[d][0] * inv, o[d][1] * inv);
    unsigned hi = pack_bf2(o[d][2] * inv, o[d][3] * inv);
    unsigned long long w = (unsigned long long)lo | ((unsigned long long)hi << 32);
    *reinterpret_cast<unsigned long long*>(
        &Prow[((2 * d + (g >> 1)) ^ (lr & 7)) * 8 + (g & 1) * 4]) = w;
  }
#pragma unroll
  for (int it = 0; it < 2; ++it) {
    int qq = it * 8 + srow;
    bf16x8 val = *reinterpret_cast<const bf16x8*>(
        &Pl[wid][qq * 64 + (((lane & 7) ^ (qq & 7)) * 8)]);
    *reinterpret_cast<bf16x8*>(
        &O[(size_t)(b * 1024 + qt * 128 + wid * 16 + qq) * 1024 + h * 64 + (lane & 7) * 8]) = val;
  }
}

extern "C" void kernel_launch(void* const* d_in, const int* in_sizes, int n_in,
                              void* d_out, int out_size, void* d_ws, size_t ws_size,
                              hipStream_t stream) {
  const float* query  = (const float*)d_in[0];
  const float* key_in = (const float*)d_in[1];
  const void*  mask_raw = d_in[2];
  const float* Wq = (const float*)d_in[3];
  const float* bq = (const float*)d_in[4];
  const float* Wk = (const float*)d_in[5];
  const float* bk = (const float*)d_in[6];
  const float* Wp = (const float*)d_in[7];
  const float* bp = (const float*)d_in[8];

  char* ws = (char*)d_ws;
  size_t off = 0;
  auto alloc = [&](size_t bytes) {
    char* p = ws + off;
    off = (off + bytes + 255) & ~(size_t)255;
    return p;
  };
  unsigned long long* packb = (unsigned long long*)alloc(512ull << 10); // [4][1024][16] u64
  short* Qbf   = (short*)alloc(8ull << 20);
  short* Kbf   = (short*)alloc(8ull << 20);   // reused as AttnO
  short* Wt3   = (short*)alloc(6ull << 20);   // Wq^T | Wk^T | Wp^T bf16
  short* Qproj = (short*)alloc(8ull << 20);
  short* Kproj = (short*)alloc(8ull << 20);
  short* Vtg   = (short*)alloc(8ull << 20);
  short* AttnO = Kbf;

  k_prep<<<7168, 256, 0, stream>>>(query, key_in, Wq, Wk, Wp,
                                   (const unsigned*)mask_raw, Qbf, Kbf, Wt3, packb);

  dim3 gqk(8, 32, 2);  // N/128, M/128, {Q,K}
  k_gemm_qk<<<gqk, 256, 0, stream>>>(Qbf, Kbf, Wt3, bq, bk, Qproj, Kproj, Vtg);

  k_attention<<<512, 512, 0, stream>>>(Qproj, Kproj, Vtg, packb, AttnO);

  k_gemm_out<<<dim3(16, 32), 256, 0, stream>>>(AttnO, Wt3 + 2 * 1024 * 1024, bp,
                                               (float*)d_out);
}